// Round 12
// baseline (254.822 us; speedup 1.0000x reference)
//
#include <hip/hip_runtime.h>
#include <math.h>

#define LN_EPS 1e-5f

typedef short short8 __attribute__((ext_vector_type(8)));
typedef float f32x4  __attribute__((ext_vector_type(4)));
typedef float f32x2  __attribute__((ext_vector_type(2)));
typedef unsigned ui32x4 __attribute__((ext_vector_type(4)));

// ---- bf16 helpers ----
__device__ __forceinline__ unsigned short f2bf(float f) {
    unsigned u = __float_as_uint(f);
    u += 0x7FFFu + ((u >> 16) & 1u);
    return (unsigned short)(u >> 16);
}
__device__ __forceinline__ unsigned packbf2(float lo, float hi) {
    return (unsigned)f2bf(lo) | ((unsigned)f2bf(hi) << 16);
}
__device__ __forceinline__ float bflo(unsigned u) { return __uint_as_float(u << 16); }
__device__ __forceinline__ float bfhi(unsigned u) { return __uint_as_float(u & 0xFFFF0000u); }

// ---- fp8 e4m3 helpers (HW cvt; word selector must be literal) ----
__device__ __forceinline__ f32x2 fp8lo(unsigned u) {
    return __builtin_amdgcn_cvt_pk_f32_fp8((int)u, false);
}
__device__ __forceinline__ f32x2 fp8hi(unsigned u) {
    return __builtin_amdgcn_cvt_pk_f32_fp8((int)u, true);
}
__device__ __forceinline__ unsigned char f2fp8(float f) {
    return (unsigned char)(__builtin_amdgcn_cvt_pk_fp8_f32(f, f, 0, false) & 0xFF);
}

// ---------------------------------------------------------------------------
// Kernel 0: transpose weights to bf16 W^T  (WT[n][k] = W[k][n]).
// ---------------------------------------------------------------------------
__global__ __launch_bounds__(256) void prep_kernel(
    const float* __restrict__ W0, const float* __restrict__ W1,
    const float* __restrict__ W2, const float* __restrict__ W3,
    unsigned short* __restrict__ T0, unsigned short* __restrict__ T1,
    unsigned short* __restrict__ T2, unsigned short* __restrict__ T3)
{
    const float* W = (blockIdx.x == 0) ? W0 : (blockIdx.x == 1) ? W1
                   : (blockIdx.x == 2) ? W2 : W3;
    unsigned short* T = (blockIdx.x == 0) ? T0 : (blockIdx.x == 1) ? T1
                      : (blockIdx.x == 2) ? T2 : T3;
    const int t = threadIdx.x;
    const int n = (t & 31) * 4;
    for (int k = t >> 5; k < 128; k += 8) {
        float4 w = ((const float4*)W)[k * 32 + (t & 31)];
        T[(n + 0) * 128 + k] = f2bf(w.x);
        T[(n + 1) * 128 + k] = f2bf(w.y);
        T[(n + 2) * 128 + k] = f2bf(w.z);
        T[(n + 3) * 128 + k] = f2bf(w.w);
    }
}

// ---------------------------------------------------------------------------
// Kernel 1: Q/K/V GEMM via bf16 MFMA + fused dst histogram.
// fp8 outputs staged in LDS then stored with coalesced uint4 writes.
// QV8 record per node = 16 chunks of 16B: [Q dims 8j..8j+7 | V dims 8j..8j+7].
// ---------------------------------------------------------------------------
__global__ __launch_bounds__(256) void qkv_mfma(
    const float* __restrict__ x,
    const unsigned short* __restrict__ WqT, const unsigned short* __restrict__ WkT,
    const unsigned short* __restrict__ WvT,
    const float* __restrict__ bq, const float* __restrict__ bk,
    const float* __restrict__ bv,
    unsigned char* __restrict__ QV8, unsigned char* __restrict__ K8,
    const int* __restrict__ dst, int E, unsigned* __restrict__ cnt, int N)
{
    __shared__ unsigned char sm[32768 + 16384];   // 48 KB
    unsigned short* xs  = (unsigned short*)sm;    // x tile (32KB), dead after afrag
    unsigned char*  qvs = sm;                     // fp8 QV staging (aliases xs)
    unsigned char*  ks  = sm + 32768;             // fp8 K staging (16KB)

    const int tid  = threadIdx.x;
    const int base = blockIdx.x * 128;

    // fused dst histogram
    for (int e = blockIdx.x * 256 + tid; e < E; e += gridDim.x * 256)
        atomicAdd(&cnt[dst[e]], 1u);

    for (int g = tid; g < 2048; g += 256) {
        int row = g >> 4, c = g & 15;
        int node = base + row;
        float4 a, b;
        if (node < N) {
            a = ((const float4*)x)[(size_t)node * 32 + c * 2];
            b = ((const float4*)x)[(size_t)node * 32 + c * 2 + 1];
        } else {
            a = make_float4(0.f, 0.f, 0.f, 0.f);
            b = a;
        }
        uint4 pk;
        pk.x = packbf2(a.x, a.y);
        pk.y = packbf2(a.z, a.w);
        pk.z = packbf2(b.x, b.y);
        pk.w = packbf2(b.z, b.w);
        int sc = c ^ (row & 15);
        *(uint4*)&xs[row * 128 + sc * 8] = pk;
    }
    __syncthreads();

    const int lane = tid & 63;
    const int w    = tid >> 6;
    const int lr   = lane & 15;
    const int lg   = lane >> 4;

    short8 afrag[2][4];
#pragma unroll
    for (int mt = 0; mt < 2; ++mt)
#pragma unroll
        for (int ko = 0; ko < 4; ++ko) {
            int row = w * 32 + mt * 16 + lr;
            int sc  = (ko * 4 + lg) ^ lr;
            afrag[mt][ko] = *(const short8*)&xs[row * 128 + sc * 8];
        }
    __syncthreads();   // xs dead; sm reused for fp8 staging

    const unsigned short* WTm[3] = {WqT, WkT, WvT};
    const float*          bm[3]  = {bq, bk, bv};

    for (int m = 0; m < 3; ++m) {
        const unsigned short* WT = WTm[m];
        f32x4 acc[2][8];
#pragma unroll
        for (int mt = 0; mt < 2; ++mt)
#pragma unroll
            for (int nt = 0; nt < 8; ++nt)
                acc[mt][nt] = (f32x4){0.f, 0.f, 0.f, 0.f};

#pragma unroll
        for (int nt = 0; nt < 8; ++nt) {
            short8 bfr[4];
#pragma unroll
            for (int ko = 0; ko < 4; ++ko) {
                int n = nt * 16 + lr;
                int k = ko * 32 + lg * 8;
                bfr[ko] = *(const short8*)&WT[n * 128 + k];
            }
#pragma unroll
            for (int mt = 0; mt < 2; ++mt)
#pragma unroll
                for (int ko = 0; ko < 4; ++ko)
                    acc[mt][nt] = __builtin_amdgcn_mfma_f32_16x16x32_bf16(
                        afrag[mt][ko], bfr[ko], acc[mt][nt], 0, 0, 0);
        }

        float bcol[8];
#pragma unroll
        for (int nt = 0; nt < 8; ++nt) bcol[nt] = bm[m][nt * 16 + lr];

#pragma unroll
        for (int mt = 0; mt < 2; ++mt)
#pragma unroll
            for (int i = 0; i < 4; ++i) {
                int row = w * 32 + mt * 16 + 4 * lg + i;
                if (m == 1) {
#pragma unroll
                    for (int nt = 0; nt < 8; ++nt)
                        ks[row * 128 + nt * 16 + lr] =
                            f2fp8(acc[mt][nt][i] + bcol[nt]);
                } else {
                    int rb = row * 256 + (m == 0 ? 0 : 8)
                           + (lr >> 3) * 16 + (lr & 7);
#pragma unroll
                    for (int nt = 0; nt < 8; ++nt)
                        qvs[rb + nt * 32] = f2fp8(acc[mt][nt][i] + bcol[nt]);
                }
            }
    }
    __syncthreads();

    for (int i = tid; i < 2048; i += 256) {          // QV: 128 rows x 16 uint4
        int row = i >> 4;
        if (base + row < N)
            *(uint4*)&QV8[(size_t)(base + row) * 256 + (i & 15) * 16] =
                *(const uint4*)&qvs[i * 16];
    }
    for (int i = tid; i < 1024; i += 256) {          // K: 128 rows x 8 uint4
        int row = i >> 3;
        if (base + row < N)
            *(uint4*)&K8[(size_t)(base + row) * 128 + (i & 7) * 16] =
                *(const uint4*)&ks[i * 16];
    }
}

// ---------------------------------------------------------------------------
// Kernel 2a: per-chunk exclusive scan (1024 elements/block) + block totals.
// ---------------------------------------------------------------------------
__global__ __launch_bounds__(1024) void scan1_kernel(
    const unsigned* __restrict__ cnt, unsigned* __restrict__ off,
    unsigned* __restrict__ bsum, int N)
{
    __shared__ unsigned sh[1024];
    const int t = threadIdx.x;
    const int gid = blockIdx.x * 1024 + t;
    unsigned v = (gid < N) ? cnt[gid] : 0u;
    sh[t] = v;
    __syncthreads();
#pragma unroll
    for (int d = 1; d < 1024; d <<= 1) {
        unsigned u = (t >= d) ? sh[t - d] : 0u;
        __syncthreads();
        sh[t] += u;
        __syncthreads();
    }
    if (gid < N) off[gid] = sh[t] - v;
    if (t == 1023) bsum[blockIdx.x] = sh[1023];
}

// ---------------------------------------------------------------------------
// Kernel 2b (merged scan2+scan3): every block redundantly scans the <=64
// block-sums in-wave, then adds its base and writes off + cursor.
// ---------------------------------------------------------------------------
__global__ __launch_bounds__(1024) void scan3_kernel(
    unsigned* __restrict__ off, unsigned* __restrict__ cursor,
    const unsigned* __restrict__ bsum, int nsc, int N)
{
    __shared__ unsigned sbase[65];   // sbase[b] = exclusive prefix of bsum
    const int t = threadIdx.x;
    if (t < 64) {
        unsigned v = (t < nsc) ? bsum[t] : 0u;
        unsigned s = v;
#pragma unroll
        for (int d = 1; d < 64; d <<= 1) {
            unsigned u = __shfl_up(s, d);
            if (t >= d) s += u;
        }
        sbase[t] = s - v;            // exclusive
        if (t == 63) sbase[64] = s;  // total
    }
    __syncthreads();
    const int gid = blockIdx.x * 1024 + t;
    if (gid < N) {
        unsigned o = off[gid] + sbase[blockIdx.x];
        off[gid] = o;
        cursor[gid] = o;
    }
    if (blockIdx.x == 0 && t == 0) off[N] = sbase[64];
}

// ---------------------------------------------------------------------------
// Kernel 3: reorder edge sources into CSR order (4B records).
// ---------------------------------------------------------------------------
__global__ __launch_bounds__(256) void reorder_kernel(
    const int* __restrict__ ei, int E,
    unsigned* __restrict__ cursor, int* __restrict__ rec_src)
{
    for (int e = blockIdx.x * blockDim.x + threadIdx.x; e < E;
         e += gridDim.x * blockDim.x) {
        int s = ei[e];
        int t = ei[E + e];
        unsigned pos = atomicAdd(&cursor[t], 1u);
        rec_src[pos] = s;
    }
}

// ---------------------------------------------------------------------------
// Kernel 4: fused per-node attention (fp8 gathers).  One wave per dst node;
// 4 edge-slots x 16 lanes, unrolled x2 (8 edges in flight).  QV gathers use
// NON-TEMPORAL loads (no L1 reuse -> bypass L1 allocation/MSHR pressure).
// aggb (bf16) written UNNORMALIZED; per-head exp-sums -> 64 partial buckets.
// ---------------------------------------------------------------------------
__global__ __launch_bounds__(256) void node_attn_kernel(
    const unsigned char* __restrict__ QV8, const unsigned char* __restrict__ K8,
    const int* __restrict__ rec_src, const unsigned* __restrict__ off,
    unsigned short* __restrict__ aggb, float* __restrict__ partials, int N)
{
    const int node = blockIdx.x * 4 + (threadIdx.x >> 6);
    if (node >= N) return;
    const int lane = threadIdx.x & 63;
    const int g = lane >> 4;
    const int j = lane & 15;
    const float scale = 0.17677669529663687f;   // 1/sqrt(32)

    const unsigned lo = off[node], hi = off[node + 1];

    const uint2 kw = *(const uint2*)&K8[(size_t)node * 128 + j * 8];
    const f32x2 ka = fp8lo(kw.x), kb = fp8hi(kw.x);
    const f32x2 kc = fp8lo(kw.y), kd = fp8hi(kw.y);

    float acc[8] = {0.f, 0.f, 0.f, 0.f, 0.f, 0.f, 0.f, 0.f};
    float ls = 0.f;

    for (unsigned i = lo; i < hi; i += 8) {
        unsigned e0 = i + g, e1 = i + 4 + g;
        bool val0 = e0 < hi, val1 = e1 < hi;
        int s0 = rec_src[val0 ? e0 : lo];
        int s1 = rec_src[val1 ? e1 : lo];
        ui32x4 r0 = __builtin_nontemporal_load(
            (const ui32x4*)&QV8[(size_t)s0 * 256 + j * 16]);
        ui32x4 r1 = __builtin_nontemporal_load(
            (const ui32x4*)&QV8[(size_t)s1 * 256 + j * 16]);

        f32x2 qa0 = fp8lo(r0[0]), qb0 = fp8hi(r0[0]);
        f32x2 qc0 = fp8lo(r0[1]), qd0 = fp8hi(r0[1]);
        f32x2 qa1 = fp8lo(r1[0]), qb1 = fp8hi(r1[0]);
        f32x2 qc1 = fp8lo(r1[1]), qd1 = fp8hi(r1[1]);

        float p0 = qa0.x * ka.x + qa0.y * ka.y + qb0.x * kb.x + qb0.y * kb.y
                 + qc0.x * kc.x + qc0.y * kc.y + qd0.x * kd.x + qd0.y * kd.y;
        float p1 = qa1.x * ka.x + qa1.y * ka.y + qb1.x * kb.x + qb1.y * kb.y
                 + qc1.x * kc.x + qc1.y * kc.y + qd1.x * kd.x + qd1.y * kd.y;

        p0 += __shfl_xor(p0, 1);
        p1 += __shfl_xor(p1, 1);
        p0 += __shfl_xor(p0, 2);
        p1 += __shfl_xor(p1, 2);   // full 32-dim head dot per 4-lane group

        float sv0 = p0 * scale;
        sv0 = (sv0 >= 0.f) ? sv0 : 0.2f * sv0;     // LeakyReLU(0.2)
        float a0 = val0 ? __expf(sv0) : 0.f;       // global softmax: no max shift
        float sv1 = p1 * scale;
        sv1 = (sv1 >= 0.f) ? sv1 : 0.2f * sv1;
        float a1 = val1 ? __expf(sv1) : 0.f;
        if ((j & 3) == 0) ls += a0 + a1;

        f32x2 va0 = fp8lo(r0[2]), vb0 = fp8hi(r0[2]);
        f32x2 vc0 = fp8lo(r0[3]), vd0 = fp8hi(r0[3]);
        f32x2 va1 = fp8lo(r1[2]), vb1 = fp8hi(r1[2]);
        f32x2 vc1 = fp8lo(r1[3]), vd1 = fp8hi(r1[3]);

        acc[0] = fmaf(a0, va0.x, acc[0]);
        acc[1] = fmaf(a0, va0.y, acc[1]);
        acc[2] = fmaf(a0, vb0.x, acc[2]);
        acc[3] = fmaf(a0, vb0.y, acc[3]);
        acc[4] = fmaf(a0, vc0.x, acc[4]);
        acc[5] = fmaf(a0, vc0.y, acc[5]);
        acc[6] = fmaf(a0, vd0.x, acc[6]);
        acc[7] = fmaf(a0, vd0.y, acc[7]);

        acc[0] = fmaf(a1, va1.x, acc[0]);
        acc[1] = fmaf(a1, va1.y, acc[1]);
        acc[2] = fmaf(a1, vb1.x, acc[2]);
        acc[3] = fmaf(a1, vb1.y, acc[3]);
        acc[4] = fmaf(a1, vc1.x, acc[4]);
        acc[5] = fmaf(a1, vc1.y, acc[5]);
        acc[6] = fmaf(a1, vd1.x, acc[6]);
        acc[7] = fmaf(a1, vd1.y, acc[7]);
    }

#pragma unroll
    for (int k = 0; k < 8; ++k) {
        acc[k] += __shfl_xor(acc[k], 16);
        acc[k] += __shfl_xor(acc[k], 32);
    }
    ls += __shfl_xor(ls, 16);
    ls += __shfl_xor(ls, 32);

    if (lane < 16) {
        uint4 o;
        o.x = packbf2(acc[0], acc[1]);
        o.y = packbf2(acc[2], acc[3]);
        o.z = packbf2(acc[4], acc[5]);
        o.w = packbf2(acc[6], acc[7]);
        *(uint4*)&aggb[(size_t)node * 128 + j * 8] = o;
        if ((j & 3) == 0)
            atomicAdd(&partials[(blockIdx.x & 63) * 4 + (j >> 2)], ls);
    }
}

// ---------------------------------------------------------------------------
// Kernel 5: h = (aggb * inv_sum) @ Wo + bo via MFMA; y = x + h; LayerNorm.
// ---------------------------------------------------------------------------
__global__ __launch_bounds__(256) void out_mfma(
    const float* __restrict__ x, const unsigned short* __restrict__ aggb,
    const unsigned short* __restrict__ WoT,
    const float* __restrict__ bo, const float* __restrict__ gamma,
    const float* __restrict__ beta, const float* __restrict__ partials,
    float* __restrict__ out, int N)
{
    __shared__ unsigned short as_[128 * 128];   // 32 KB, swizzled
    __shared__ float invs[4];
    const int tid  = threadIdx.x;
    const int base = blockIdx.x * 128;

    if (tid < 64) {
        float4 ps = ((const float4*)partials)[tid];
#pragma unroll
        for (int m = 1; m < 64; m <<= 1) {
            ps.x += __shfl_xor(ps.x, m);
            ps.y += __shfl_xor(ps.y, m);
            ps.z += __shfl_xor(ps.z, m);
            ps.w += __shfl_xor(ps.w, m);
        }
        if (tid == 0) {
            invs[0] = 1.f / ps.x; invs[1] = 1.f / ps.y;
            invs[2] = 1.f / ps.z; invs[3] = 1.f / ps.w;
        }
    }
    __syncthreads();

    for (int g = tid; g < 2048; g += 256) {
        int row = g >> 4, c = g & 15;
        int node = base + row;
        uint4 v = (node < N) ? *(const uint4*)&aggb[(size_t)node * 128 + c * 8]
                             : make_uint4(0u, 0u, 0u, 0u);
        float iv = invs[c >> 2];
        uint4 pk;
        pk.x = packbf2(bflo(v.x) * iv, bfhi(v.x) * iv);
        pk.y = packbf2(bflo(v.y) * iv, bfhi(v.y) * iv);
        pk.z = packbf2(bflo(v.z) * iv, bfhi(v.z) * iv);
        pk.w = packbf2(bflo(v.w) * iv, bfhi(v.w) * iv);
        int sc = c ^ (row & 15);
        *(uint4*)&as_[row * 128 + sc * 8] = pk;
    }
    __syncthreads();

    const int lane = tid & 63;
    const int w    = tid >> 6;
    const int lr   = lane & 15;
    const int lg   = lane >> 4;

    short8 afrag[2][4];
#pragma unroll
    for (int mt = 0; mt < 2; ++mt)
#pragma unroll
        for (int ko = 0; ko < 4; ++ko) {
            int row = w * 32 + mt * 16 + lr;
            int sc  = (ko * 4 + lg) ^ lr;
            afrag[mt][ko] = *(const short8*)&as_[row * 128 + sc * 8];
        }

    f32x4 acc[2][8];
#pragma unroll
    for (int mt = 0; mt < 2; ++mt)
#pragma unroll
        for (int nt = 0; nt < 8; ++nt)
            acc[mt][nt] = (f32x4){0.f, 0.f, 0.f, 0.f};

#pragma unroll
    for (int nt = 0; nt < 8; ++nt) {
        short8 bfr[4];
#pragma unroll
        for (int ko = 0; ko < 4; ++ko) {
            int n = nt * 16 + lr;
            int k = ko * 32 + lg * 8;
            bfr[ko] = *(const short8*)&WoT[n * 128 + k];
        }
#pragma unroll
        for (int mt = 0; mt < 2; ++mt)
#pragma unroll
            for (int ko = 0; ko < 4; ++ko)
                acc[mt][nt] = __builtin_amdgcn_mfma_f32_16x16x32_bf16(
                    afrag[mt][ko], bfr[ko], acc[mt][nt], 0, 0, 0);
    }

    float bo8[8], gg8[8], bb8[8];
#pragma unroll
    for (int nt = 0; nt < 8; ++nt) {
        bo8[nt] = bo[nt * 16 + lr];
        gg8[nt] = gamma[nt * 16 + lr];
        bb8[nt] = beta[nt * 16 + lr];
    }

#pragma unroll
    for (int mt = 0; mt < 2; ++mt)
#pragma unroll
        for (int i = 0; i < 4; ++i) {
            int node = base + w * 32 + mt * 16 + 4 * lg + i;
            if (node >= N) continue;
            float y8[8];
            float ps = 0.f;
#pragma unroll
            for (int nt = 0; nt < 8; ++nt) {
                float y = acc[mt][nt][i] + bo8[nt]
                        + x[(size_t)node * 128 + nt * 16 + lr];
                y8[nt] = y;
                ps += y;
            }
#pragma unroll
            for (int m = 1; m < 16; m <<= 1) ps += __shfl_xor(ps, m);
            float mu = ps * (1.0f / 128.0f);

            float pv = 0.f;
#pragma unroll
            for (int nt = 0; nt < 8; ++nt) {
                float d = y8[nt] - mu;
                pv = fmaf(d, d, pv);
            }
#pragma unroll
            for (int m = 1; m < 16; m <<= 1) pv += __shfl_xor(pv, m);
            float rstd = rsqrtf(pv * (1.0f / 128.0f) + LN_EPS);

#pragma unroll
            for (int nt = 0; nt < 8; ++nt)
                out[(size_t)node * 128 + nt * 16 + lr] =
                    (y8[nt] - mu) * rstd * gg8[nt] + bb8[nt];
        }
}

// ---------------------------------------------------------------------------
extern "C" void kernel_launch(void* const* d_in, const int* in_sizes, int n_in,
                              void* d_out, int out_size, void* d_ws, size_t ws_size,
                              hipStream_t stream)
{
    const float* x     = (const float*)d_in[0];
    const int*   ei    = (const int*)d_in[1];
    const float* Wq    = (const float*)d_in[2];
    const float* bq    = (const float*)d_in[3];
    const float* Wk    = (const float*)d_in[4];
    const float* bk    = (const float*)d_in[5];
    const float* Wv    = (const float*)d_in[6];
    const float* bv    = (const float*)d_in[7];
    const float* Wo    = (const float*)d_in[8];
    const float* bo    = (const float*)d_in[9];
    const float* gamma = (const float*)d_in[10];
    const float* beta  = (const float*)d_in[11];
    float* out = (float*)d_out;

    const int N = in_sizes[0] / 128;
    const int E = in_sizes[1] / 2;

    // workspace layout
    char* p = (char*)d_ws;
    unsigned char*  QV8  = (unsigned char*)p;  p += (size_t)N * 256;   // fp8 Q||V
    unsigned char*  K8   = (unsigned char*)p;  p += (size_t)N * 128;   // fp8 K
    unsigned short* aggb = (unsigned short*)p; p += (size_t)N * 128 * 2;
    int* rec_src = (int*)p; p += (size_t)E * 4;
    unsigned short* WqT = (unsigned short*)p; p += 16384 * 2;
    unsigned short* WkT = (unsigned short*)p; p += 16384 * 2;
    unsigned short* WvT = (unsigned short*)p; p += 16384 * 2;
    unsigned short* WoT = (unsigned short*)p; p += 16384 * 2;
    float*    partials = (float*)p;  p += 256 * 4;          // 64 buckets x 4 heads
    unsigned* cnt      = (unsigned*)p; p += (size_t)N * 4;
    unsigned* off      = (unsigned*)p; p += (size_t)(N + 1) * 4;
    unsigned* cursor   = (unsigned*)p; p += (size_t)N * 4;
    unsigned* bsum     = (unsigned*)p; p += 64 * 4;

    // zero partials + cnt (contiguous)
    (void)hipMemsetAsync(partials, 0, (size_t)(256 + N) * sizeof(unsigned), stream);

    const int nb  = (N + 127) / 128;
    const int nsc = (N + 1023) / 1024;   // <= 64 for N <= 65536
    prep_kernel<<<4, 256, 0, stream>>>(Wq, Wk, Wv, Wo, WqT, WkT, WvT, WoT);
    qkv_mfma<<<nb, 256, 0, stream>>>(x, WqT, WkT, WvT, bq, bk, bv,
                                     QV8, K8, ei + E, E, cnt, N);
    scan1_kernel<<<nsc, 1024, 0, stream>>>(cnt, off, bsum, N);
    scan3_kernel<<<nsc, 1024, 0, stream>>>(off, cursor, bsum, nsc, N);
    reorder_kernel<<<1024, 256, 0, stream>>>(ei, E, cursor, rec_src);
    node_attn_kernel<<<(N + 3) / 4, 256, 0, stream>>>(QV8, K8, rec_src, off,
                                                      aggb, partials, N);
    out_mfma<<<nb, 256, 0, stream>>>(x, aggb, WoT, bo, gamma, beta, partials,
                                     out, N);
}

// Round 13
// 248.171 us; speedup vs baseline: 1.0268x; 1.0268x over previous
//
#include <hip/hip_runtime.h>
#include <math.h>

#define LN_EPS 1e-5f

typedef short short8 __attribute__((ext_vector_type(8)));
typedef float f32x4  __attribute__((ext_vector_type(4)));
typedef float f32x2  __attribute__((ext_vector_type(2)));

// ---- bf16 helpers ----
__device__ __forceinline__ unsigned short f2bf(float f) {
    unsigned u = __float_as_uint(f);
    u += 0x7FFFu + ((u >> 16) & 1u);
    return (unsigned short)(u >> 16);
}
__device__ __forceinline__ unsigned packbf2(float lo, float hi) {
    return (unsigned)f2bf(lo) | ((unsigned)f2bf(hi) << 16);
}
__device__ __forceinline__ float bflo(unsigned u) { return __uint_as_float(u << 16); }
__device__ __forceinline__ float bfhi(unsigned u) { return __uint_as_float(u & 0xFFFF0000u); }

// ---- fp8 e4m3 helpers (HW cvt; word selector must be literal) ----
__device__ __forceinline__ f32x2 fp8lo(unsigned u) {
    return __builtin_amdgcn_cvt_pk_f32_fp8((int)u, false);
}
__device__ __forceinline__ f32x2 fp8hi(unsigned u) {
    return __builtin_amdgcn_cvt_pk_f32_fp8((int)u, true);
}
__device__ __forceinline__ unsigned char f2fp8(float f) {
    return (unsigned char)(__builtin_amdgcn_cvt_pk_fp8_f32(f, f, 0, false) & 0xFF);
}

// ---- int4 encode: value v -> biased nibble round(v*2)+8 in [0,15] ----
__device__ __forceinline__ int f2n4(float v) {
    int n = (int)rintf(v * 2.f) + 8;
    return n < 0 ? 0 : (n > 15 ? 15 : n);
}

// ---------------------------------------------------------------------------
// Kernel 0: weight transpose to bf16 W^T (blocks 0-3) + zero cnt/partials
// (blocks 4+) — replaces the separate hipMemsetAsync.
// ---------------------------------------------------------------------------
__global__ __launch_bounds__(256) void prep_kernel(
    const float* __restrict__ W0, const float* __restrict__ W1,
    const float* __restrict__ W2, const float* __restrict__ W3,
    unsigned short* __restrict__ T0, unsigned short* __restrict__ T1,
    unsigned short* __restrict__ T2, unsigned short* __restrict__ T3,
    unsigned* __restrict__ zbase, int zcount)
{
    if (blockIdx.x >= 4) {
        const int nz = (gridDim.x - 4) * 256;
        for (int i = (blockIdx.x - 4) * 256 + threadIdx.x; i < zcount; i += nz)
            zbase[i] = 0u;
        return;
    }
    const float* W = (blockIdx.x == 0) ? W0 : (blockIdx.x == 1) ? W1
                   : (blockIdx.x == 2) ? W2 : W3;
    unsigned short* T = (blockIdx.x == 0) ? T0 : (blockIdx.x == 1) ? T1
                      : (blockIdx.x == 2) ? T2 : T3;
    const int t = threadIdx.x;
    const int n = (t & 31) * 4;
    for (int k = t >> 5; k < 128; k += 8) {
        float4 w = ((const float4*)W)[k * 32 + (t & 31)];
        T[(n + 0) * 128 + k] = f2bf(w.x);
        T[(n + 1) * 128 + k] = f2bf(w.y);
        T[(n + 2) * 128 + k] = f2bf(w.z);
        T[(n + 3) * 128 + k] = f2bf(w.w);
    }
}

// ---------------------------------------------------------------------------
// Kernel 1: Q/K/V GEMM via bf16 MFMA + fused dst histogram.
// Q,V -> int4 (biased nibbles, scale 2): QV4 record = 128B/node, chunk jp
// (0..7) = 16B: [Q nibbles dims 16jp..16jp+15 (8B) | V nibbles (8B)].
// K -> fp8, 128B/node.  All staged in LDS, stored coalesced.
// ---------------------------------------------------------------------------
__global__ __launch_bounds__(256) void qkv_mfma(
    const float* __restrict__ x,
    const unsigned short* __restrict__ WqT, const unsigned short* __restrict__ WkT,
    const unsigned short* __restrict__ WvT,
    const float* __restrict__ bq, const float* __restrict__ bk,
    const float* __restrict__ bv,
    unsigned char* __restrict__ QV4, unsigned char* __restrict__ K8,
    const int* __restrict__ dst, int E, unsigned* __restrict__ cnt, int N)
{
    __shared__ unsigned char sm[32768];           // 32 KB
    unsigned short* xs   = (unsigned short*)sm;   // x tile, dead after afrag
    unsigned char*  qv4s = sm;                    // int4 QV staging (16KB)
    unsigned char*  ks   = sm + 16384;            // fp8 K staging (16KB)

    const int tid  = threadIdx.x;
    const int base = blockIdx.x * 128;

    // fused dst histogram
    for (int e = blockIdx.x * 256 + tid; e < E; e += gridDim.x * 256)
        atomicAdd(&cnt[dst[e]], 1u);

    for (int g = tid; g < 2048; g += 256) {
        int row = g >> 4, c = g & 15;
        int node = base + row;
        float4 a, b;
        if (node < N) {
            a = ((const float4*)x)[(size_t)node * 32 + c * 2];
            b = ((const float4*)x)[(size_t)node * 32 + c * 2 + 1];
        } else {
            a = make_float4(0.f, 0.f, 0.f, 0.f);
            b = a;
        }
        uint4 pk;
        pk.x = packbf2(a.x, a.y);
        pk.y = packbf2(a.z, a.w);
        pk.z = packbf2(b.x, b.y);
        pk.w = packbf2(b.z, b.w);
        int sc = c ^ (row & 15);
        *(uint4*)&xs[row * 128 + sc * 8] = pk;
    }
    __syncthreads();

    const int lane = tid & 63;
    const int w    = tid >> 6;
    const int lr   = lane & 15;
    const int lg   = lane >> 4;

    short8 afrag[2][4];
#pragma unroll
    for (int mt = 0; mt < 2; ++mt)
#pragma unroll
        for (int ko = 0; ko < 4; ++ko) {
            int row = w * 32 + mt * 16 + lr;
            int sc  = (ko * 4 + lg) ^ lr;
            afrag[mt][ko] = *(const short8*)&xs[row * 128 + sc * 8];
        }
    __syncthreads();   // xs dead; sm reused for staging

    const unsigned short* WTm[3] = {WqT, WkT, WvT};
    const float*          bm[3]  = {bq, bk, bv};

    for (int m = 0; m < 3; ++m) {
        const unsigned short* WT = WTm[m];
        f32x4 acc[2][8];
#pragma unroll
        for (int mt = 0; mt < 2; ++mt)
#pragma unroll
            for (int nt = 0; nt < 8; ++nt)
                acc[mt][nt] = (f32x4){0.f, 0.f, 0.f, 0.f};

#pragma unroll
        for (int nt = 0; nt < 8; ++nt) {
            short8 bfr[4];
#pragma unroll
            for (int ko = 0; ko < 4; ++ko) {
                int n = nt * 16 + lr;
                int k = ko * 32 + lg * 8;
                bfr[ko] = *(const short8*)&WT[n * 128 + k];
            }
#pragma unroll
            for (int mt = 0; mt < 2; ++mt)
#pragma unroll
                for (int ko = 0; ko < 4; ++ko)
                    acc[mt][nt] = __builtin_amdgcn_mfma_f32_16x16x32_bf16(
                        afrag[mt][ko], bfr[ko], acc[mt][nt], 0, 0, 0);
        }

        float bcol[8];
#pragma unroll
        for (int nt = 0; nt < 8; ++nt) bcol[nt] = bm[m][nt * 16 + lr];

#pragma unroll
        for (int mt = 0; mt < 2; ++mt)
#pragma unroll
            for (int i = 0; i < 4; ++i) {
                int row = w * 32 + mt * 16 + 4 * lg + i;
                if (m == 1) {
#pragma unroll
                    for (int nt = 0; nt < 8; ++nt)
                        ks[row * 128 + nt * 16 + lr] =
                            f2fp8(acc[mt][nt][i] + bcol[nt]);
                } else {
                    const int boff = (m == 0) ? 0 : 8;
#pragma unroll
                    for (int nt = 0; nt < 8; ++nt) {
                        int nib = f2n4(acc[mt][nt][i] + bcol[nt]);
                        int oth = __shfl_xor(nib, 1);   // partner col (lr^1)
                        if (!(lr & 1))
                            qv4s[row * 128 + nt * 16 + boff + (lr >> 1)] =
                                (unsigned char)(nib | (oth << 4));
                    }
                }
            }
    }
    __syncthreads();

    for (int i = tid; i < 1024; i += 256) {          // QV4: 128 rows x 8 uint4
        int row = i >> 3;
        if (base + row < N)
            *(uint4*)&QV4[(size_t)(base + row) * 128 + (i & 7) * 16] =
                *(const uint4*)&qv4s[i * 16];
    }
    for (int i = tid; i < 1024; i += 256) {          // K8: 128 rows x 8 uint4
        int row = i >> 3;
        if (base + row < N)
            *(uint4*)&K8[(size_t)(base + row) * 128 + (i & 7) * 16] =
                *(const uint4*)&ks[i * 16];
    }
}

// ---------------------------------------------------------------------------
// Kernel 2a: per-chunk exclusive scan (1024 elements/block) + block totals.
// ---------------------------------------------------------------------------
__global__ __launch_bounds__(1024) void scan1_kernel(
    const unsigned* __restrict__ cnt, unsigned* __restrict__ off,
    unsigned* __restrict__ bsum, int N)
{
    __shared__ unsigned sh[1024];
    const int t = threadIdx.x;
    const int gid = blockIdx.x * 1024 + t;
    unsigned v = (gid < N) ? cnt[gid] : 0u;
    sh[t] = v;
    __syncthreads();
#pragma unroll
    for (int d = 1; d < 1024; d <<= 1) {
        unsigned u = (t >= d) ? sh[t - d] : 0u;
        __syncthreads();
        sh[t] += u;
        __syncthreads();
    }
    if (gid < N) off[gid] = sh[t] - v;
    if (t == 1023) bsum[blockIdx.x] = sh[1023];
}

// ---------------------------------------------------------------------------
// Kernel 2b: every block redundantly scans the <=64 block-sums in-wave,
// then adds its base and writes off + cursor.
// ---------------------------------------------------------------------------
__global__ __launch_bounds__(1024) void scan3_kernel(
    unsigned* __restrict__ off, unsigned* __restrict__ cursor,
    const unsigned* __restrict__ bsum, int nsc, int N)
{
    __shared__ unsigned sbase[65];
    const int t = threadIdx.x;
    if (t < 64) {
        unsigned v = (t < nsc) ? bsum[t] : 0u;
        unsigned s = v;
#pragma unroll
        for (int d = 1; d < 64; d <<= 1) {
            unsigned u = __shfl_up(s, d);
            if (t >= d) s += u;
        }
        sbase[t] = s - v;
        if (t == 63) sbase[64] = s;
    }
    __syncthreads();
    const int gid = blockIdx.x * 1024 + t;
    if (gid < N) {
        unsigned o = off[gid] + sbase[blockIdx.x];
        off[gid] = o;
        cursor[gid] = o;
    }
    if (blockIdx.x == 0 && t == 0) off[N] = sbase[64];
}

// ---------------------------------------------------------------------------
// Kernel 3: reorder edge sources into CSR order (4B records).
// ---------------------------------------------------------------------------
__global__ __launch_bounds__(256) void reorder_kernel(
    const int* __restrict__ ei, int E,
    unsigned* __restrict__ cursor, int* __restrict__ rec_src)
{
    for (int e = blockIdx.x * blockDim.x + threadIdx.x; e < E;
         e += gridDim.x * blockDim.x) {
        int s = ei[e];
        int t = ei[E + e];
        unsigned pos = atomicAdd(&cursor[t], 1u);
        rec_src[pos] = s;
    }
}

// ---------------------------------------------------------------------------
// Kernel 4: fused per-node attention, int4 Q/V gathers (2 cache lines/edge
// instead of 4 — the random-line service rate is the measured binder).
// One wave per dst node; 8 edge-slots x 8 lanes; lane jp covers dims
// [16jp,16jp+16).  Score uses  sum(nq*k) - 8*sum(k)  (k fp8, per-node);
// V uses  0.5*(sum(a*nv) - 8*sum_node(a))  folded at writeout.
// ---------------------------------------------------------------------------
__global__ __launch_bounds__(256) void node_attn_kernel(
    const unsigned char* __restrict__ QV4, const unsigned char* __restrict__ K8,
    const int* __restrict__ rec_src, const unsigned* __restrict__ off,
    unsigned short* __restrict__ aggb, float* __restrict__ partials, int N)
{
    const int node = blockIdx.x * 4 + (threadIdx.x >> 6);
    if (node >= N) return;
    const int lane = threadIdx.x & 63;
    const int g  = lane >> 3;      // edge slot 0..7
    const int jp = lane & 7;       // dim chunk; head = jp>>1
    const float scale2 = 0.0883883476f;   // 0.5 / sqrt(32)

    const unsigned lo = off[node], hi = off[node + 1];

    // K[node] dims [16jp,16jp+16) decoded once
    const uint4 kw = *(const uint4*)&K8[(size_t)node * 128 + jp * 16];
    float kk[16];
    {
        f32x2 t;
        t = fp8lo(kw.x); kk[0] = t.x;  kk[1] = t.y;
        t = fp8hi(kw.x); kk[2] = t.x;  kk[3] = t.y;
        t = fp8lo(kw.y); kk[4] = t.x;  kk[5] = t.y;
        t = fp8hi(kw.y); kk[6] = t.x;  kk[7] = t.y;
        t = fp8lo(kw.z); kk[8] = t.x;  kk[9] = t.y;
        t = fp8hi(kw.z); kk[10] = t.x; kk[11] = t.y;
        t = fp8lo(kw.w); kk[12] = t.x; kk[13] = t.y;
        t = fp8hi(kw.w); kk[14] = t.x; kk[15] = t.y;
    }
    float ksum8 = 0.f;
#pragma unroll
    for (int d = 0; d < 16; ++d) ksum8 += kk[d];
    ksum8 *= 8.f;

    float acc[16];
#pragma unroll
    for (int d = 0; d < 16; ++d) acc[d] = 0.f;
    float ls = 0.f;

    for (unsigned i = lo; i < hi; i += 8) {
        unsigned e = i + g;
        bool valid = e < hi;
        int s = rec_src[valid ? e : lo];
        uint4 r = *(const uint4*)&QV4[(size_t)s * 128 + jp * 16];

        float p = -ksum8;
#pragma unroll
        for (int d = 0; d < 8; ++d)
            p = fmaf((float)((r.x >> (4 * d)) & 15u), kk[d], p);
#pragma unroll
        for (int d = 0; d < 8; ++d)
            p = fmaf((float)((r.y >> (4 * d)) & 15u), kk[8 + d], p);
        p += __shfl_xor(p, 1);        // 32-dim head dot across lane pair

        float sv = p * scale2;
        sv = (sv >= 0.f) ? sv : 0.2f * sv;    // LeakyReLU(0.2)
        float a = valid ? __expf(sv) : 0.f;   // global softmax: no max shift
        if (!(jp & 1)) ls += a;

#pragma unroll
        for (int d = 0; d < 8; ++d)
            acc[d] = fmaf(a, (float)((r.z >> (4 * d)) & 15u), acc[d]);
#pragma unroll
        for (int d = 0; d < 8; ++d)
            acc[8 + d] = fmaf(a, (float)((r.w >> (4 * d)) & 15u), acc[8 + d]);
    }

#pragma unroll
    for (int d = 0; d < 16; ++d) {
        acc[d] += __shfl_xor(acc[d], 8);
        acc[d] += __shfl_xor(acc[d], 16);
        acc[d] += __shfl_xor(acc[d], 32);
    }
    ls += __shfl_xor(ls, 8);
    ls += __shfl_xor(ls, 16);
    ls += __shfl_xor(ls, 32);
    float lsn = __shfl_xor(ls, 1);
    float asum = (jp & 1) ? lsn : ls;   // node-local sum(a) for this head

    if (lane < 8) {
        float o[16];
#pragma unroll
        for (int d = 0; d < 16; ++d) o[d] = 0.5f * (acc[d] - 8.f * asum);
        uint4 w0, w1;
        w0.x = packbf2(o[0], o[1]);   w0.y = packbf2(o[2], o[3]);
        w0.z = packbf2(o[4], o[5]);   w0.w = packbf2(o[6], o[7]);
        w1.x = packbf2(o[8], o[9]);   w1.y = packbf2(o[10], o[11]);
        w1.z = packbf2(o[12], o[13]); w1.w = packbf2(o[14], o[15]);
        *(uint4*)&aggb[(size_t)node * 128 + jp * 16]     = w0;
        *(uint4*)&aggb[(size_t)node * 128 + jp * 16 + 8] = w1;
        if (!(jp & 1))
            atomicAdd(&partials[(blockIdx.x & 63) * 4 + (jp >> 1)], ls);
    }
}

// ---------------------------------------------------------------------------
// Kernel 5: h = (aggb * inv_sum) @ Wo + bo via MFMA; y = x + h; LayerNorm.
// ---------------------------------------------------------------------------
__global__ __launch_bounds__(256) void out_mfma(
    const float* __restrict__ x, const unsigned short* __restrict__ aggb,
    const unsigned short* __restrict__ WoT,
    const float* __restrict__ bo, const float* __restrict__ gamma,
    const float* __restrict__ beta, const float* __restrict__ partials,
    float* __restrict__ out, int N)
{
    __shared__ unsigned short as_[128 * 128];   // 32 KB, swizzled
    __shared__ float invs[4];
    const int tid  = threadIdx.x;
    const int base = blockIdx.x * 128;

    if (tid < 64) {
        float4 ps = ((const float4*)partials)[tid];
#pragma unroll
        for (int m = 1; m < 64; m <<= 1) {
            ps.x += __shfl_xor(ps.x, m);
            ps.y += __shfl_xor(ps.y, m);
            ps.z += __shfl_xor(ps.z, m);
            ps.w += __shfl_xor(ps.w, m);
        }
        if (tid == 0) {
            invs[0] = 1.f / ps.x; invs[1] = 1.f / ps.y;
            invs[2] = 1.f / ps.z; invs[3] = 1.f / ps.w;
        }
    }
    __syncthreads();

    for (int g = tid; g < 2048; g += 256) {
        int row = g >> 4, c = g & 15;
        int node = base + row;
        uint4 v = (node < N) ? *(const uint4*)&aggb[(size_t)node * 128 + c * 8]
                             : make_uint4(0u, 0u, 0u, 0u);
        float iv = invs[c >> 2];
        uint4 pk;
        pk.x = packbf2(bflo(v.x) * iv, bfhi(v.x) * iv);
        pk.y = packbf2(bflo(v.y) * iv, bfhi(v.y) * iv);
        pk.z = packbf2(bflo(v.z) * iv, bfhi(v.z) * iv);
        pk.w = packbf2(bflo(v.w) * iv, bfhi(v.w) * iv);
        int sc = c ^ (row & 15);
        *(uint4*)&as_[row * 128 + sc * 8] = pk;
    }
    __syncthreads();

    const int lane = tid & 63;
    const int w    = tid >> 6;
    const int lr   = lane & 15;
    const int lg   = lane >> 4;

    short8 afrag[2][4];
#pragma unroll
    for (int mt = 0; mt < 2; ++mt)
#pragma unroll
        for (int ko = 0; ko < 4; ++ko) {
            int row = w * 32 + mt * 16 + lr;
            int sc  = (ko * 4 + lg) ^ lr;
            afrag[mt][ko] = *(const short8*)&as_[row * 128 + sc * 8];
        }

    f32x4 acc[2][8];
#pragma unroll
    for (int mt = 0; mt < 2; ++mt)
#pragma unroll
        for (int nt = 0; nt < 8; ++nt)
            acc[mt][nt] = (f32x4){0.f, 0.f, 0.f, 0.f};

#pragma unroll
    for (int nt = 0; nt < 8; ++nt) {
        short8 bfr[4];
#pragma unroll
        for (int ko = 0; ko < 4; ++ko) {
            int n = nt * 16 + lr;
            int k = ko * 32 + lg * 8;
            bfr[ko] = *(const short8*)&WoT[n * 128 + k];
        }
#pragma unroll
        for (int mt = 0; mt < 2; ++mt)
#pragma unroll
            for (int ko = 0; ko < 4; ++ko)
                acc[mt][nt] = __builtin_amdgcn_mfma_f32_16x16x32_bf16(
                    afrag[mt][ko], bfr[ko], acc[mt][nt], 0, 0, 0);
    }

    float bo8[8], gg8[8], bb8[8];
#pragma unroll
    for (int nt = 0; nt < 8; ++nt) {
        bo8[nt] = bo[nt * 16 + lr];
        gg8[nt] = gamma[nt * 16 + lr];
        bb8[nt] = beta[nt * 16 + lr];
    }

#pragma unroll
    for (int mt = 0; mt < 2; ++mt)
#pragma unroll
        for (int i = 0; i < 4; ++i) {
            int node = base + w * 32 + mt * 16 + 4 * lg + i;
            if (node >= N) continue;
            float y8[8];
            float ps = 0.f;
#pragma unroll
            for (int nt = 0; nt < 8; ++nt) {
                float y = acc[mt][nt][i] + bo8[nt]
                        + x[(size_t)node * 128 + nt * 16 + lr];
                y8[nt] = y;
                ps += y;
            }
#pragma unroll
            for (int m = 1; m < 16; m <<= 1) ps += __shfl_xor(ps, m);
            float mu = ps * (1.0f / 128.0f);

            float pv = 0.f;
#pragma unroll
            for (int nt = 0; nt < 8; ++nt) {
                float d = y8[nt] - mu;
                pv = fmaf(d, d, pv);
            }
#pragma unroll
            for (int m = 1; m < 16; m <<= 1) pv += __shfl_xor(pv, m);
            float rstd = rsqrtf(pv * (1.0f / 128.0f) + LN_EPS);

#pragma unroll
            for (int nt = 0; nt < 8; ++nt)
                out[(size_t)node * 128 + nt * 16 + lr] =
                    (y8[nt] - mu) * rstd * gg8[nt] + bb8[nt];
        }
}

// ---------------------------------------------------------------------------
extern "C" void kernel_launch(void* const* d_in, const int* in_sizes, int n_in,
                              void* d_out, int out_size, void* d_ws, size_t ws_size,
                              hipStream_t stream)
{
    const float* x     = (const float*)d_in[0];
    const int*   ei    = (const int*)d_in[1];
    const float* Wq    = (const float*)d_in[2];
    const float* bq    = (const float*)d_in[3];
    const float* Wk    = (const float*)d_in[4];
    const float* bk    = (const float*)d_in[5];
    const float* Wv    = (const float*)d_in[6];
    const float* bv    = (const float*)d_in[7];
    const float* Wo    = (const float*)d_in[8];
    const float* bo    = (const float*)d_in[9];
    const float* gamma = (const float*)d_in[10];
    const float* beta  = (const float*)d_in[11];
    float* out = (float*)d_out;

    const int N = in_sizes[0] / 128;
    const int E = in_sizes[1] / 2;

    // workspace layout
    char* p = (char*)d_ws;
    unsigned char*  QV4  = (unsigned char*)p;  p += (size_t)N * 128;   // int4 Q||V
    unsigned char*  K8   = (unsigned char*)p;  p += (size_t)N * 128;   // fp8 K
    unsigned short* aggb = (unsigned short*)p; p += (size_t)N * 128 * 2;
    int* rec_src = (int*)p; p += (size_t)E * 4;
    unsigned short* WqT = (unsigned short*)p; p += 16384 * 2;
    unsigned short* WkT = (unsigned short*)p; p += 16384 * 2;
    unsigned short* WvT = (unsigned short*)p; p += 16384 * 2;
    unsigned short* WoT = (unsigned short*)p; p += 16384 * 2;
    float*    partials = (float*)p;  p += 256 * 4;          // 64 buckets x 4 heads
    unsigned* cnt      = (unsigned*)p; p += (size_t)N * 4;
    unsigned* off      = (unsigned*)p; p += (size_t)(N + 1) * 4;
    unsigned* cursor   = (unsigned*)p; p += (size_t)N * 4;
    unsigned* bsum     = (unsigned*)p; p += 64 * 4;

    const int nb  = (N + 127) / 128;
    const int nsc = (N + 1023) / 1024;   // <= 64 for N <= 65536

    // prep: 4 transpose blocks + 13 zero blocks (zeroes partials+cnt)
    prep_kernel<<<17, 256, 0, stream>>>(Wq, Wk, Wv, Wo, WqT, WkT, WvT, WoT,
                                        (unsigned*)partials, 256 + N);
    qkv_mfma<<<nb, 256, 0, stream>>>(x, WqT, WkT, WvT, bq, bk, bv,
                                     QV4, K8, ei + E, E, cnt, N);
    scan1_kernel<<<nsc, 1024, 0, stream>>>(cnt, off, bsum, N);
    scan3_kernel<<<nsc, 1024, 0, stream>>>(off, cursor, bsum, nsc, N);
    reorder_kernel<<<1024, 256, 0, stream>>>(ei, E, cursor, rec_src);
    node_attn_kernel<<<(N + 3) / 4, 256, 0, stream>>>(QV4, K8, rec_src, off,
                                                      aggb, partials, N);
    out_mfma<<<nb, 256, 0, stream>>>(x, aggb, WoT, bo, gamma, beta, partials,
                                     out, N);
}

// Round 14
// 209.002 us; speedup vs baseline: 1.2192x; 1.1874x over previous
//
#include <hip/hip_runtime.h>
#include <math.h>

#define LN_EPS 1e-5f

typedef short short8 __attribute__((ext_vector_type(8)));
typedef float f32x4  __attribute__((ext_vector_type(4)));
typedef float f32x2  __attribute__((ext_vector_type(2)));

// ---- bf16 helpers ----
__device__ __forceinline__ unsigned short f2bf(float f) {
    unsigned u = __float_as_uint(f);
    u += 0x7FFFu + ((u >> 16) & 1u);
    return (unsigned short)(u >> 16);
}
__device__ __forceinline__ unsigned packbf2(float lo, float hi) {
    return (unsigned)f2bf(lo) | ((unsigned)f2bf(hi) << 16);
}
__device__ __forceinline__ float bflo(unsigned u) { return __uint_as_float(u << 16); }
__device__ __forceinline__ float bfhi(unsigned u) { return __uint_as_float(u & 0xFFFF0000u); }

// ---- fp8 e4m3 helpers (HW cvt; word selector must be literal) ----
__device__ __forceinline__ f32x2 fp8lo(unsigned u) {
    return __builtin_amdgcn_cvt_pk_f32_fp8((int)u, false);
}
__device__ __forceinline__ f32x2 fp8hi(unsigned u) {
    return __builtin_amdgcn_cvt_pk_f32_fp8((int)u, true);
}
__device__ __forceinline__ unsigned char f2fp8(float f) {
    return (unsigned char)(__builtin_amdgcn_cvt_pk_fp8_f32(f, f, 0, false) & 0xFF);
}

// ---- int4 encode: value v -> biased nibble round(v*2)+8 in [0,15] ----
__device__ __forceinline__ int f2n4(float v) {
    int n = (int)rintf(v * 2.f) + 8;
    return n < 0 ? 0 : (n > 15 ? 15 : n);
}

// ---------------------------------------------------------------------------
// Kernel 0: weight transpose to bf16 W^T (blocks 0-3) + zero partials/cnt.
// ---------------------------------------------------------------------------
__global__ __launch_bounds__(256) void prep_kernel(
    const float* __restrict__ W0, const float* __restrict__ W1,
    const float* __restrict__ W2, const float* __restrict__ W3,
    unsigned short* __restrict__ T0, unsigned short* __restrict__ T1,
    unsigned short* __restrict__ T2, unsigned short* __restrict__ T3,
    unsigned* __restrict__ zbase, int zcount)
{
    if (blockIdx.x >= 4) {
        const int nz = (gridDim.x - 4) * 256;
        for (int i = (blockIdx.x - 4) * 256 + threadIdx.x; i < zcount; i += nz)
            zbase[i] = 0u;
        return;
    }
    const float* W = (blockIdx.x == 0) ? W0 : (blockIdx.x == 1) ? W1
                   : (blockIdx.x == 2) ? W2 : W3;
    unsigned short* T = (blockIdx.x == 0) ? T0 : (blockIdx.x == 1) ? T1
                      : (blockIdx.x == 2) ? T2 : T3;
    const int t = threadIdx.x;
    const int n = (t & 31) * 4;
    for (int k = t >> 5; k < 128; k += 8) {
        float4 w = ((const float4*)W)[k * 32 + (t & 31)];
        T[(n + 0) * 128 + k] = f2bf(w.x);
        T[(n + 1) * 128 + k] = f2bf(w.y);
        T[(n + 2) * 128 + k] = f2bf(w.z);
        T[(n + 3) * 128 + k] = f2bf(w.w);
    }
}

// ---------------------------------------------------------------------------
// Kernel 1: Q/K/V GEMM via bf16 MFMA + fused dst histogram.
// int4 layout (private): Q/V byte b (b in [0,64)) holds dims (b, b+64) as
// (lo,hi) nibbles -> both cols owned by the SAME lane (nt and nt+4), so
// packing needs no cross-lane shuffles.  QV4 record = 128B/node, chunk jp =
// [Q bytes 8jp..8jp+8 | V bytes 8jp..8jp+8].  K8 = fp8 linear, 128B/node.
// ---------------------------------------------------------------------------
__global__ __launch_bounds__(256) void qkv_mfma(
    const float* __restrict__ x,
    const unsigned short* __restrict__ WqT, const unsigned short* __restrict__ WkT,
    const unsigned short* __restrict__ WvT,
    const float* __restrict__ bq, const float* __restrict__ bk,
    const float* __restrict__ bv,
    unsigned char* __restrict__ QV4, unsigned char* __restrict__ K8,
    const int* __restrict__ dst, int E, unsigned* __restrict__ cnt, int N)
{
    __shared__ unsigned char sm[32768];           // 32 KB
    unsigned short* xs   = (unsigned short*)sm;   // x tile, dead after afrag
    unsigned char*  qv4s = sm;                    // int4 QV staging (16KB)
    unsigned char*  ks   = sm + 16384;            // fp8 K staging (16KB)

    const int tid  = threadIdx.x;
    const int base = blockIdx.x * 128;

    for (int e = blockIdx.x * 256 + tid; e < E; e += gridDim.x * 256)
        atomicAdd(&cnt[dst[e]], 1u);

    for (int g = tid; g < 2048; g += 256) {
        int row = g >> 4, c = g & 15;
        int node = base + row;
        float4 a, b;
        if (node < N) {
            a = ((const float4*)x)[(size_t)node * 32 + c * 2];
            b = ((const float4*)x)[(size_t)node * 32 + c * 2 + 1];
        } else {
            a = make_float4(0.f, 0.f, 0.f, 0.f);
            b = a;
        }
        uint4 pk;
        pk.x = packbf2(a.x, a.y);
        pk.y = packbf2(a.z, a.w);
        pk.z = packbf2(b.x, b.y);
        pk.w = packbf2(b.z, b.w);
        int sc = c ^ (row & 15);
        *(uint4*)&xs[row * 128 + sc * 8] = pk;
    }
    __syncthreads();

    const int lane = tid & 63;
    const int w    = tid >> 6;
    const int lr   = lane & 15;
    const int lg   = lane >> 4;

    short8 afrag[2][4];
#pragma unroll
    for (int mt = 0; mt < 2; ++mt)
#pragma unroll
        for (int ko = 0; ko < 4; ++ko) {
            int row = w * 32 + mt * 16 + lr;
            int sc  = (ko * 4 + lg) ^ lr;
            afrag[mt][ko] = *(const short8*)&xs[row * 128 + sc * 8];
        }
    __syncthreads();   // xs dead; sm reused for staging

    const unsigned short* WTm[3] = {WqT, WkT, WvT};
    const float*          bm[3]  = {bq, bk, bv};

    for (int m = 0; m < 3; ++m) {
        const unsigned short* WT = WTm[m];
        f32x4 acc[2][8];
#pragma unroll
        for (int mt = 0; mt < 2; ++mt)
#pragma unroll
            for (int nt = 0; nt < 8; ++nt)
                acc[mt][nt] = (f32x4){0.f, 0.f, 0.f, 0.f};

#pragma unroll
        for (int nt = 0; nt < 8; ++nt) {
            short8 bfr[4];
#pragma unroll
            for (int ko = 0; ko < 4; ++ko) {
                int n = nt * 16 + lr;
                int k = ko * 32 + lg * 8;
                bfr[ko] = *(const short8*)&WT[n * 128 + k];
            }
#pragma unroll
            for (int mt = 0; mt < 2; ++mt)
#pragma unroll
                for (int ko = 0; ko < 4; ++ko)
                    acc[mt][nt] = __builtin_amdgcn_mfma_f32_16x16x32_bf16(
                        afrag[mt][ko], bfr[ko], acc[mt][nt], 0, 0, 0);
        }

        float bcol[8];
#pragma unroll
        for (int nt = 0; nt < 8; ++nt) bcol[nt] = bm[m][nt * 16 + lr];

#pragma unroll
        for (int mt = 0; mt < 2; ++mt)
#pragma unroll
            for (int i = 0; i < 4; ++i) {
                int row = w * 32 + mt * 16 + 4 * lg + i;
                if (m == 1) {
#pragma unroll
                    for (int nt = 0; nt < 8; ++nt)
                        ks[row * 128 + nt * 16 + lr] =
                            f2fp8(acc[mt][nt][i] + bcol[nt]);
                } else {
                    const int boff = (m == 0) ? 0 : 8;
#pragma unroll
                    for (int nt = 0; nt < 4; ++nt) {
                        int nlo = f2n4(acc[mt][nt][i]     + bcol[nt]);
                        int nhi = f2n4(acc[mt][nt + 4][i] + bcol[nt + 4]);
                        // byte b = nt*16+lr: chunk b>>3, pos b&7
                        qv4s[row * 128 + (2 * nt + (lr >> 3)) * 16 + boff + (lr & 7)]
                            = (unsigned char)(nlo | (nhi << 4));
                    }
                }
            }
    }
    __syncthreads();

    for (int i = tid; i < 1024; i += 256) {          // QV4: 128 rows x 8 uint4
        int row = i >> 3;
        if (base + row < N)
            *(uint4*)&QV4[(size_t)(base + row) * 128 + (i & 7) * 16] =
                *(const uint4*)&qv4s[i * 16];
    }
    for (int i = tid; i < 1024; i += 256) {          // K8: 128 rows x 8 uint4
        int row = i >> 3;
        if (base + row < N)
            *(uint4*)&K8[(size_t)(base + row) * 128 + (i & 7) * 16] =
                *(const uint4*)&ks[i * 16];
    }
}

// ---------------------------------------------------------------------------
// Kernel 2a: per-chunk exclusive scan + block totals.
// ---------------------------------------------------------------------------
__global__ __launch_bounds__(1024) void scan1_kernel(
    const unsigned* __restrict__ cnt, unsigned* __restrict__ off,
    unsigned* __restrict__ bsum, int N)
{
    __shared__ unsigned sh[1024];
    const int t = threadIdx.x;
    const int gid = blockIdx.x * 1024 + t;
    unsigned v = (gid < N) ? cnt[gid] : 0u;
    sh[t] = v;
    __syncthreads();
#pragma unroll
    for (int d = 1; d < 1024; d <<= 1) {
        unsigned u = (t >= d) ? sh[t - d] : 0u;
        __syncthreads();
        sh[t] += u;
        __syncthreads();
    }
    if (gid < N) off[gid] = sh[t] - v;
    if (t == 1023) bsum[blockIdx.x] = sh[1023];
}

// ---------------------------------------------------------------------------
// Kernel 2b: redundant block-sum scan per block; writes off + cursor.
// ---------------------------------------------------------------------------
__global__ __launch_bounds__(1024) void scan3_kernel(
    unsigned* __restrict__ off, unsigned* __restrict__ cursor,
    const unsigned* __restrict__ bsum, int nsc, int N)
{
    __shared__ unsigned sbase[65];
    const int t = threadIdx.x;
    if (t < 64) {
        unsigned v = (t < nsc) ? bsum[t] : 0u;
        unsigned s = v;
#pragma unroll
        for (int d = 1; d < 64; d <<= 1) {
            unsigned u = __shfl_up(s, d);
            if (t >= d) s += u;
        }
        sbase[t] = s - v;
        if (t == 63) sbase[64] = s;
    }
    __syncthreads();
    const int gid = blockIdx.x * 1024 + t;
    if (gid < N) {
        unsigned o = off[gid] + sbase[blockIdx.x];
        off[gid] = o;
        cursor[gid] = o;
    }
    if (blockIdx.x == 0 && t == 0) off[N] = sbase[64];
}

// ---------------------------------------------------------------------------
// Kernel 3: reorder edge sources into CSR order.
// ---------------------------------------------------------------------------
__global__ __launch_bounds__(256) void reorder_kernel(
    const int* __restrict__ ei, int E,
    unsigned* __restrict__ cursor, int* __restrict__ rec_src)
{
    for (int e = blockIdx.x * blockDim.x + threadIdx.x; e < E;
         e += gridDim.x * blockDim.x) {
        int s = ei[e];
        int t = ei[E + e];
        unsigned pos = atomicAdd(&cursor[t], 1u);
        rec_src[pos] = s;
    }
}

// ---------------------------------------------------------------------------
// Kernel 4: fused per-node attention, int4 paired-nibble gathers.
// Lane jp (0..7) owns dims [8jp,8jp+8) (lo stream, head jp>>2) and
// [64+8jp, 64+8jp+8) (hi stream, head 2+(jp>>2)).  8 edge slots x 8 lanes.
// Softmax partial sums: per-block LDS combine -> 4 atomics per BLOCK into
// 64B-padded buckets (de-serializes the old 200k same-line atomics).
// ---------------------------------------------------------------------------
__global__ __launch_bounds__(256) void node_attn_kernel(
    const unsigned char* __restrict__ QV4, const unsigned char* __restrict__ K8,
    const int* __restrict__ rec_src, const unsigned* __restrict__ off,
    unsigned short* __restrict__ aggb, float* __restrict__ partials, int N)
{
    __shared__ float lsum[4][4];   // [wave][head]
    const int wv   = threadIdx.x >> 6;
    const int lane = threadIdx.x & 63;
    const int node = blockIdx.x * 4 + wv;
    const bool vnode = node < N;
    const int g  = lane >> 3;      // edge slot 0..7
    const int jp = lane & 7;       // dim chunk
    const float scale2 = 0.0883883476f;   // 0.5 / sqrt(32)

    unsigned lo = 0, hi = 0;
    if (vnode) { lo = off[node]; hi = off[node + 1]; }

    // K dims for this lane's two streams
    float kkl[8], kkh[8];
    if (vnode) {
        uint2 kwl = *(const uint2*)&K8[(size_t)node * 128 + jp * 8];
        uint2 kwh = *(const uint2*)&K8[(size_t)node * 128 + 64 + jp * 8];
        f32x2 t;
        t = fp8lo(kwl.x); kkl[0] = t.x; kkl[1] = t.y;
        t = fp8hi(kwl.x); kkl[2] = t.x; kkl[3] = t.y;
        t = fp8lo(kwl.y); kkl[4] = t.x; kkl[5] = t.y;
        t = fp8hi(kwl.y); kkl[6] = t.x; kkl[7] = t.y;
        t = fp8lo(kwh.x); kkh[0] = t.x; kkh[1] = t.y;
        t = fp8hi(kwh.x); kkh[2] = t.x; kkh[3] = t.y;
        t = fp8lo(kwh.y); kkh[4] = t.x; kkh[5] = t.y;
        t = fp8hi(kwh.y); kkh[6] = t.x; kkh[7] = t.y;
    } else {
#pragma unroll
        for (int d = 0; d < 8; ++d) { kkl[d] = 0.f; kkh[d] = 0.f; }
    }
    float ksl8 = 0.f, ksh8 = 0.f;
#pragma unroll
    for (int d = 0; d < 8; ++d) { ksl8 += kkl[d]; ksh8 += kkh[d]; }
    ksl8 *= 8.f; ksh8 *= 8.f;

    float accl[8], acch[8];
#pragma unroll
    for (int d = 0; d < 8; ++d) { accl[d] = 0.f; acch[d] = 0.f; }
    float lsl = 0.f, lshv = 0.f;

    for (unsigned i = lo; i < hi; i += 8) {
        unsigned e = i + g;
        bool valid = e < hi;
        int s = rec_src[valid ? e : lo];
        uint4 r = *(const uint4*)&QV4[(size_t)s * 128 + jp * 16];

        float pl = -ksl8, ph = -ksh8;
#pragma unroll
        for (int d = 0; d < 4; ++d) {
            unsigned b = (r.x >> (8 * d)) & 0xFFu;
            pl = fmaf((float)(b & 15u), kkl[d], pl);
            ph = fmaf((float)(b >> 4),  kkh[d], ph);
        }
#pragma unroll
        for (int d = 0; d < 4; ++d) {
            unsigned b = (r.y >> (8 * d)) & 0xFFu;
            pl = fmaf((float)(b & 15u), kkl[4 + d], pl);
            ph = fmaf((float)(b >> 4),  kkh[4 + d], ph);
        }
        pl += __shfl_xor(pl, 1);
        ph += __shfl_xor(ph, 1);
        pl += __shfl_xor(pl, 2);
        ph += __shfl_xor(ph, 2);   // head dots across the 4-lane group

        float svl = pl * scale2;
        svl = (svl >= 0.f) ? svl : 0.2f * svl;    // LeakyReLU(0.2)
        float al = valid ? __expf(svl) : 0.f;     // global softmax: no max shift
        float svh = ph * scale2;
        svh = (svh >= 0.f) ? svh : 0.2f * svh;
        float ah = valid ? __expf(svh) : 0.f;
        if (!(jp & 3)) { lsl += al; lshv += ah; }

#pragma unroll
        for (int d = 0; d < 4; ++d) {
            unsigned b = (r.z >> (8 * d)) & 0xFFu;
            accl[d] = fmaf(al, (float)(b & 15u), accl[d]);
            acch[d] = fmaf(ah, (float)(b >> 4),  acch[d]);
        }
#pragma unroll
        for (int d = 0; d < 4; ++d) {
            unsigned b = (r.w >> (8 * d)) & 0xFFu;
            accl[4 + d] = fmaf(al, (float)(b & 15u), accl[4 + d]);
            acch[4 + d] = fmaf(ah, (float)(b >> 4),  acch[4 + d]);
        }
    }

#pragma unroll
    for (int d = 0; d < 8; ++d) {
        accl[d] += __shfl_xor(accl[d], 8);
        acch[d] += __shfl_xor(acch[d], 8);
        accl[d] += __shfl_xor(accl[d], 16);
        acch[d] += __shfl_xor(acch[d], 16);
        accl[d] += __shfl_xor(accl[d], 32);
        acch[d] += __shfl_xor(acch[d], 32);
    }
    lsl  += __shfl_xor(lsl, 8);
    lshv += __shfl_xor(lshv, 8);
    lsl  += __shfl_xor(lsl, 16);
    lshv += __shfl_xor(lshv, 16);
    lsl  += __shfl_xor(lsl, 32);
    lshv += __shfl_xor(lshv, 32);
    // lane jp=0: lsl = sum_a(head0), lshv = head2 ; lane jp=4: head1, head3
    float asl = __shfl(lsl,  (jp >> 2) * 4);   // this lane's lo-head sum
    float ash = __shfl(lshv, (jp >> 2) * 4);   // this lane's hi-head sum

    if (lane < 8 && vnode) {
        float ol[8], oh[8];
#pragma unroll
        for (int d = 0; d < 8; ++d) {
            ol[d] = 0.5f * (accl[d] - 8.f * asl);
            oh[d] = 0.5f * (acch[d] - 8.f * ash);
        }
        uint4 w0, w1;
        w0.x = packbf2(ol[0], ol[1]); w0.y = packbf2(ol[2], ol[3]);
        w0.z = packbf2(ol[4], ol[5]); w0.w = packbf2(ol[6], ol[7]);
        w1.x = packbf2(oh[0], oh[1]); w1.y = packbf2(oh[2], oh[3]);
        w1.z = packbf2(oh[4], oh[5]); w1.w = packbf2(oh[6], oh[7]);
        *(uint4*)&aggb[(size_t)node * 128 + jp * 8]      = w0;  // dims 8jp..
        *(uint4*)&aggb[(size_t)node * 128 + 64 + jp * 8] = w1;  // dims 64+8jp..
    }

    // per-block combine of softmax sums, then 4 padded atomics per block
    if (lane == 0) { lsum[wv][0] = vnode ? lsl : 0.f; lsum[wv][2] = vnode ? lshv : 0.f; }
    if (lane == 4) { lsum[wv][1] = vnode ? lsl : 0.f; lsum[wv][3] = vnode ? lshv : 0.f; }
    __syncthreads();
    if (threadIdx.x < 4) {
        float v = lsum[0][threadIdx.x] + lsum[1][threadIdx.x]
                + lsum[2][threadIdx.x] + lsum[3][threadIdx.x];
        atomicAdd(&partials[((blockIdx.x & 63) * 4 + threadIdx.x) * 16], v);
    }
}

// ---------------------------------------------------------------------------
// Kernel 5: h = (aggb * inv_sum) @ Wo + bo via MFMA; y = x + h; LayerNorm.
// ---------------------------------------------------------------------------
__global__ __launch_bounds__(256) void out_mfma(
    const float* __restrict__ x, const unsigned short* __restrict__ aggb,
    const unsigned short* __restrict__ WoT,
    const float* __restrict__ bo, const float* __restrict__ gamma,
    const float* __restrict__ beta, const float* __restrict__ partials,
    float* __restrict__ out, int N)
{
    __shared__ unsigned short as_[128 * 128];   // 32 KB, swizzled
    __shared__ float invs[4];
    const int tid  = threadIdx.x;
    const int base = blockIdx.x * 128;

    if (tid < 64) {
        float p0 = partials[(tid * 4 + 0) * 16];
        float p1 = partials[(tid * 4 + 1) * 16];
        float p2 = partials[(tid * 4 + 2) * 16];
        float p3 = partials[(tid * 4 + 3) * 16];
#pragma unroll
        for (int m = 1; m < 64; m <<= 1) {
            p0 += __shfl_xor(p0, m);
            p1 += __shfl_xor(p1, m);
            p2 += __shfl_xor(p2, m);
            p3 += __shfl_xor(p3, m);
        }
        if (tid == 0) {
            invs[0] = 1.f / p0; invs[1] = 1.f / p1;
            invs[2] = 1.f / p2; invs[3] = 1.f / p3;
        }
    }
    __syncthreads();

    for (int g = tid; g < 2048; g += 256) {
        int row = g >> 4, c = g & 15;
        int node = base + row;
        uint4 v = (node < N) ? *(const uint4*)&aggb[(size_t)node * 128 + c * 8]
                             : make_uint4(0u, 0u, 0u, 0u);
        float iv = invs[c >> 2];   // chunk c = dims [8c,8c+8) -> head c>>2
        uint4 pk;
        pk.x = packbf2(bflo(v.x) * iv, bfhi(v.x) * iv);
        pk.y = packbf2(bflo(v.y) * iv, bfhi(v.y) * iv);
        pk.z = packbf2(bflo(v.z) * iv, bfhi(v.z) * iv);
        pk.w = packbf2(bflo(v.w) * iv, bfhi(v.w) * iv);
        int sc = c ^ (row & 15);
        *(uint4*)&as_[row * 128 + sc * 8] = pk;
    }
    __syncthreads();

    const int lane = tid & 63;
    const int w    = tid >> 6;
    const int lr   = lane & 15;
    const int lg   = lane >> 4;

    short8 afrag[2][4];
#pragma unroll
    for (int mt = 0; mt < 2; ++mt)
#pragma unroll
        for (int ko = 0; ko < 4; ++ko) {
            int row = w * 32 + mt * 16 + lr;
            int sc  = (ko * 4 + lg) ^ lr;
            afrag[mt][ko] = *(const short8*)&as_[row * 128 + sc * 8];
        }

    f32x4 acc[2][8];
#pragma unroll
    for (int mt = 0; mt < 2; ++mt)
#pragma unroll
        for (int nt = 0; nt < 8; ++nt)
            acc[mt][nt] = (f32x4){0.f, 0.f, 0.f, 0.f};

#pragma unroll
    for (int nt = 0; nt < 8; ++nt) {
        short8 bfr[4];
#pragma unroll
        for (int ko = 0; ko < 4; ++ko) {
            int n = nt * 16 + lr;
            int k = ko * 32 + lg * 8;
            bfr[ko] = *(const short8*)&WoT[n * 128 + k];
        }
#pragma unroll
        for (int mt = 0; mt < 2; ++mt)
#pragma unroll
            for (int ko = 0; ko < 4; ++ko)
                acc[mt][nt] = __builtin_amdgcn_mfma_f32_16x16x32_bf16(
                    afrag[mt][ko], bfr[ko], acc[mt][nt], 0, 0, 0);
    }

    float bo8[8], gg8[8], bb8[8];
#pragma unroll
    for (int nt = 0; nt < 8; ++nt) {
        bo8[nt] = bo[nt * 16 + lr];
        gg8[nt] = gamma[nt * 16 + lr];
        bb8[nt] = beta[nt * 16 + lr];
    }

#pragma unroll
    for (int mt = 0; mt < 2; ++mt)
#pragma unroll
        for (int i = 0; i < 4; ++i) {
            int node = base + w * 32 + mt * 16 + 4 * lg + i;
            if (node >= N) continue;
            float y8[8];
            float ps = 0.f;
#pragma unroll
            for (int nt = 0; nt < 8; ++nt) {
                float y = acc[mt][nt][i] + bo8[nt]
                        + x[(size_t)node * 128 + nt * 16 + lr];
                y8[nt] = y;
                ps += y;
            }
#pragma unroll
            for (int m = 1; m < 16; m <<= 1) ps += __shfl_xor(ps, m);
            float mu = ps * (1.0f / 128.0f);

            float pv = 0.f;
#pragma unroll
            for (int nt = 0; nt < 8; ++nt) {
                float d = y8[nt] - mu;
                pv = fmaf(d, d, pv);
            }
#pragma unroll
            for (int m = 1; m < 16; m <<= 1) pv += __shfl_xor(pv, m);
            float rstd = rsqrtf(pv * (1.0f / 128.0f) + LN_EPS);

#pragma unroll
            for (int nt = 0; nt < 8; ++nt)
                out[(size_t)node * 128 + nt * 16 + lr] =
                    (y8[nt] - mu) * rstd * gg8[nt] + bb8[nt];
        }
}

// ---------------------------------------------------------------------------
extern "C" void kernel_launch(void* const* d_in, const int* in_sizes, int n_in,
                              void* d_out, int out_size, void* d_ws, size_t ws_size,
                              hipStream_t stream)
{
    const float* x     = (const float*)d_in[0];
    const int*   ei    = (const int*)d_in[1];
    const float* Wq    = (const float*)d_in[2];
    const float* bq    = (const float*)d_in[3];
    const float* Wk    = (const float*)d_in[4];
    const float* bk    = (const float*)d_in[5];
    const float* Wv    = (const float*)d_in[6];
    const float* bv    = (const float*)d_in[7];
    const float* Wo    = (const float*)d_in[8];
    const float* bo    = (const float*)d_in[9];
    const float* gamma = (const float*)d_in[10];
    const float* beta  = (const float*)d_in[11];
    float* out = (float*)d_out;

    const int N = in_sizes[0] / 128;
    const int E = in_sizes[1] / 2;

    // workspace layout
    char* p = (char*)d_ws;
    unsigned char*  QV4  = (unsigned char*)p;  p += (size_t)N * 128;   // int4 Q||V
    unsigned char*  K8   = (unsigned char*)p;  p += (size_t)N * 128;   // fp8 K
    unsigned short* aggb = (unsigned short*)p; p += (size_t)N * 128 * 2;
    int* rec_src = (int*)p; p += (size_t)E * 4;
    unsigned short* WqT = (unsigned short*)p; p += 16384 * 2;
    unsigned short* WkT = (unsigned short*)p; p += 16384 * 2;
    unsigned short* WvT = (unsigned short*)p; p += 16384 * 2;
    unsigned short* WoT = (unsigned short*)p; p += 16384 * 2;
    float*    partials = (float*)p;  p += 4096 * 4;    // 256 buckets x 64B pad
    unsigned* cnt      = (unsigned*)p; p += (size_t)N * 4;
    unsigned* off      = (unsigned*)p; p += (size_t)(N + 1) * 4;
    unsigned* cursor   = (unsigned*)p; p += (size_t)N * 4;
    unsigned* bsum     = (unsigned*)p; p += 64 * 4;

    const int nb  = (N + 127) / 128;
    const int nsc = (N + 1023) / 1024;   // <= 64 for N <= 65536

    // prep: 4 transpose blocks + zero blocks (partials_pad + cnt contiguous)
    prep_kernel<<<20, 256, 0, stream>>>(Wq, Wk, Wv, Wo, WqT, WkT, WvT, WoT,
                                        (unsigned*)partials, 4096 + N);
    qkv_mfma<<<nb, 256, 0, stream>>>(x, WqT, WkT, WvT, bq, bk, bv,
                                     QV4, K8, ei + E, E, cnt, N);
    scan1_kernel<<<nsc, 1024, 0, stream>>>(cnt, off, bsum, N);
    scan3_kernel<<<nsc, 1024, 0, stream>>>(off, cursor, bsum, nsc, N);
    reorder_kernel<<<1024, 256, 0, stream>>>(ei, E, cursor, rec_src);
    node_attn_kernel<<<(N + 3) / 4, 256, 0, stream>>>(QV4, K8, rec_src, off,
                                                      aggb, partials, N);
    out_mfma<<<nb, 256, 0, stream>>>(x, aggb, WoT, bo, gamma, beta, partials,
                                     out, N);
}